// Round 10
// baseline (261.708 us; speedup 1.0000x reference)
//
#include <hip/hip_runtime.h>

// B=8192 rows, N=4096 omegas/row, W=1000 bins, L=101 Legendre terms.
// Exact simplifications (verified r3/r4/r9):
//   * pdf normalization cancels in grad/pdf -> skipped
//   * sigma<=0.6 rows are pure elementwise -omega/sigma^2
//   * series terms beyond l=16 underflow for sigma>0.6 -> fixed L=17 unroll
// Round-10: r9 proved source-level register pins CANNOT beat the register
// allocator (VGPR stayed 24 -> loads still serialized). This round removes
// registers from the memory pipeline entirely: global_load_lds DMA stages
// both the 4KB pdf table AND the 16KB omega row into wave-private LDS,
// with hand-placed counted s_waitcnt vmcnt(N) (never 0, AITER-style):
//   issue [t0..t3, o0..o3] -> vmcnt(4) (table ready, om in flight)
//   per k: vmcnt(3) (om_k ready; prior stores keep queue at 4) -> gather
// No __syncthreads anywhere (wave-private LDS regions). Pad T[1000]=p[998]
// is written by build_tables into tabs so staging needs no register fixup.

#define L_TERMS 101
#define W_BINS 1000
#define N_COLS 4096
#define TPB 256
#define TRANS_STRIDE 1024   // padded transpose row stride
#define TAB_STRIDE 1024     // floats per pdf-table row in workspace
#define PAD_W 1004          // (fallback kernel only)
#define GRAD_T 0.6f
#define L_FIX 17            // fixed term count, exact for sigma > 0.6

typedef float v4f __attribute__((ext_vector_type(4)));

typedef const __attribute__((address_space(1))) void gas_void;
typedef __attribute__((address_space(3))) void las_void;

__device__ __forceinline__ void dma16(const float* g, float* l) {
  // 16B per lane, wave-uniform LDS base + lane*16, per-lane global src.
  __builtin_amdgcn_global_load_lds((gas_void*)g, (las_void*)l, 16, 0, 0);
}

// ---------------------------------------------------------------------------
// Transpose sine_terms [1000][101] -> sine_t [101][1024] (padded)
__global__ __launch_bounds__(128) void transpose_sine(
    const float* __restrict__ sine, float* __restrict__ sine_t) {
  int w = blockIdx.x;   // 0..999
  int t = threadIdx.x;  // 0..127
  if (t < L_TERMS) sine_t[(size_t)t * TRANS_STRIDE + w] = sine[(size_t)w * L_TERMS + t];
}

// ---------------------------------------------------------------------------
// Kernel A: per series-row pdf table -> tabs[b][0..999] + pad tabs[b][1000].
__global__ __launch_bounds__(TPB, 6) void build_tables(
    const float* __restrict__ sigmas,
    const float* __restrict__ sine_t,   // [101][1024]
    float* __restrict__ tabs) {         // [B][1024]
  const int b = blockIdx.x;
  const float s = sigmas[b];
  if (s <= GRAD_T) return;              // gaussian row: no table needed

  const int tid = threadIdx.x;
  const int w0 = tid * 4;
  if (w0 >= W_BINS) return;

  float e[L_FIX];
  const float ns2 = -0.5f * s * s;
#pragma unroll
  for (int l = 0; l < L_FIX; ++l)
    e[l] = __expf(ns2 * (float)(l * (l + 1)));

  float acc[4] = {0.0f, 0.0f, 0.0f, 0.0f};
#pragma unroll
  for (int l = 0; l < L_FIX; ++l) {
    v4f sv = *(const v4f*)(sine_t + (size_t)l * TRANS_STRIDE + w0);
    acc[0] = fmaf(e[l], sv.x, acc[0]);
    acc[1] = fmaf(e[l], sv.y, acc[1]);
    acc[2] = fmaf(e[l], sv.z, acc[2]);
    acc[3] = fmaf(e[l], sv.w, acc[3]);
  }
  v4f r = {acc[0], acc[1], acc[2], acc[3]};
  *(v4f*)(tabs + (size_t)b * TAB_STRIDE + w0) = r;
  if (w0 == 996) tabs[(size_t)b * TAB_STRIDE + 1000] = acc[2];  // pad = p[998]
}

// ---------------------------------------------------------------------------
// Kernel B: DMA streamer. Wave-private LDS staging, counted vmcnt waits,
// zero barriers, zero load-data VGPRs.
__global__ __launch_bounds__(TPB, 5) void igso3_gather(
    const float* __restrict__ sigmas,
    const float* __restrict__ omegas,
    const float* __restrict__ omega_grid,
    const float* __restrict__ tabs,
    float* __restrict__ out) {
  __shared__ float s_tab[4][1024];   // wave-private pdf tables (T[1000]=p[998])
  __shared__ float s_om[4][1024];    // wave-private omega quadrants

  const int tid = threadIdx.x;
  const int wv  = tid >> 6;    // wave 0..3
  const int ln  = tid & 63;    // lane
  const int b = blockIdx.x;
  const float s = sigmas[b];
  const bool ser = s > GRAD_T;

  const float* om_row = omegas + (size_t)b * N_COLS;
  v4f* __restrict__ out4 = (v4f*)(out + (size_t)b * N_COLS);

  float* mytab = s_tab[wv];
  float* myom  = s_om[wv];

  // ---- issue all DMAs up front: queue = [t0..t3, o0..o3] (ser) or [o0..o3]
  if (ser) {
    const float* tb = tabs + (size_t)b * TAB_STRIDE + ln * 4;
#pragma unroll
    for (int k = 0; k < 4; ++k) dma16(tb + k * 256, mytab + k * 256);
  }
  {
    // wave wv's om quadrant k covers global floats [k*1024 + wv*256 .. +255]
    const float* ob = om_row + wv * 256 + ln * 4;
#pragma unroll
    for (int k = 0; k < 4; ++k) dma16(ob + k * 1024, myom + k * 256);
  }

  const float bw = omega_grid[1] - omega_grid[0];
  const float inv_bw = 1.0f / bw;

  if (ser) {
    asm volatile("s_waitcnt vmcnt(4)" ::: "memory");   // table resident; om in flight
#pragma unroll
    for (int k = 0; k < 4; ++k) {
      // queue before this wait: [o_k..o_3, stores...] = 4 entries; oldest = o_k
      asm volatile("s_waitcnt vmcnt(3)" ::: "memory");
      v4f om = *(const v4f*)(myom + k * 256 + ln * 4);
      float o[4] = {om.x, om.y, om.z, om.w};
      float rv[4];
#pragma unroll
      for (int j = 0; j < 4; ++j) {
        // omega >= 0 -> int-cast == floor; idx in [0,1000]
        int idx = (int)fmaf(o[j], inv_bw, 0.5f);
        idx = min(idx, 1000);
        float shift = fmaf(-((float)idx + 0.5f), bw, o[j]);
        int bidx = max(idx - 1, 0);
        float lv = mytab[bidx];          // ds_read2_b32 pair
        float rt = mytab[bidx + 1];
        // pdf_pad semantics: left=p[max(idx-1,0)]; right=p[idx] (idx<1000),
        // p[998] (idx=1000, = T[1000]); idx==0 -> right=left=p[0].
        float right = (idx == 0) ? lv : rt;
        float grad = (right - lv) * inv_bw;
        float accu = fmaf(shift, grad, lv);
        rv[j] = grad * __builtin_amdgcn_rcpf(accu);
      }
      v4f res = {rv[0], rv[1], rv[2], rv[3]};
      out4[k * 256 + tid] = res;
    }
  } else {
    const float inv_s2 = __builtin_amdgcn_rcpf(s * s);
#pragma unroll
    for (int k = 0; k < 4; ++k) {
      asm volatile("s_waitcnt vmcnt(3)" ::: "memory");
      v4f om = *(const v4f*)(myom + k * 256 + ln * 4);
      v4f res = om * (-inv_s2);
      out4[k * 256 + tid] = res;
    }
  }
}

// ---------------------------------------------------------------------------
// Fallback (no workspace): r3-verified combined kernel, untransposed input.
__global__ __launch_bounds__(TPB, 6) void igso3_main_nt(
    const float* __restrict__ sigmas,
    const float* __restrict__ omegas,
    const float* __restrict__ omega_grid,
    const float* __restrict__ sine_src,  // [1000][101]
    float* __restrict__ out) {
  __shared__ float s_pdf[PAD_W];

  const int tid = threadIdx.x;
  const int b = blockIdx.x;

  const v4f* __restrict__ om4 = (const v4f*)(omegas + (size_t)b * N_COLS);
  v4f* __restrict__ out4 = (v4f*)(out + (size_t)b * N_COLS);

  v4f om[4];
#pragma unroll
  for (int k = 0; k < 4; ++k) om[k] = om4[k * TPB + tid];

  const float s = sigmas[b];
  const float bw = omega_grid[1] - omega_grid[0];
  const float inv_bw = 1.0f / bw;

  if (s <= GRAD_T) {
    const float inv_s2 = __builtin_amdgcn_rcpf(s * s);
#pragma unroll
    for (int k = 0; k < 4; ++k) {
      out4[k * TPB + tid] = om[k] * (-inv_s2);
    }
    return;
  }

  float e[L_FIX];
  const float ns2 = -0.5f * s * s;
#pragma unroll
  for (int l = 0; l < L_FIX; ++l) e[l] = __expf(ns2 * (float)(l * (l + 1)));

  const int w0 = tid * 4;
  float acc[4] = {0.0f, 0.0f, 0.0f, 0.0f};
  if (w0 < W_BINS) {
#pragma unroll
    for (int l = 0; l < L_FIX; ++l) {
#pragma unroll
      for (int j = 0; j < 4; ++j)
        acc[j] = fmaf(e[l], sine_src[(size_t)(w0 + j) * L_TERMS + l], acc[j]);
    }
#pragma unroll
    for (int j = 0; j < 4; ++j) s_pdf[w0 + 1 + j] = acc[j];
    if (tid == 0) s_pdf[0] = acc[0];
    if (w0 == 996) s_pdf[1001] = acc[2];
  }
  __syncthreads();

#pragma unroll
  for (int k = 0; k < 4; ++k) {
    float o[4] = {om[k].x, om[k].y, om[k].z, om[k].w};
    float rv[4];
#pragma unroll
    for (int j = 0; j < 4; ++j) {
      int idx = (int)fmaf(o[j], inv_bw, 0.5f);
      idx = min(idx, 1000);
      float shift = fmaf(-((float)idx + 0.5f), bw, o[j]);
      float left  = s_pdf[idx];
      float right = s_pdf[idx + 1];
      float grad = (right - left) * inv_bw;
      float accu = fmaf(shift, grad, left);
      rv[j] = grad * __builtin_amdgcn_rcpf(accu);
    }
    v4f res = {rv[0], rv[1], rv[2], rv[3]};
    out4[k * TPB + tid] = res;
  }
}

// ---------------------------------------------------------------------------
extern "C" void kernel_launch(void* const* d_in, const int* in_sizes, int n_in,
                              void* d_out, int out_size, void* d_ws, size_t ws_size,
                              hipStream_t stream) {
  const float* sigmas     = (const float*)d_in[0];
  const float* omegas     = (const float*)d_in[1];
  const float* omega_grid = (const float*)d_in[2];
  // d_in[3] = ls (unused)
  const float* sine_terms = (const float*)d_in[4];
  float* out = (float*)d_out;

  const int B = in_sizes[0];  // 8192 -> one block per row

  const size_t tab_bytes   = (size_t)B * TAB_STRIDE * sizeof(float);      // 32 MB
  const size_t trans_bytes = (size_t)L_TERMS * TRANS_STRIDE * sizeof(float); // 404 KB

  if (ws_size >= tab_bytes + trans_bytes) {
    float* tabs   = (float*)d_ws;
    float* sine_t = (float*)((char*)d_ws + tab_bytes);
    transpose_sine<<<W_BINS, 128, 0, stream>>>(sine_terms, sine_t);
    build_tables<<<B, TPB, 0, stream>>>(sigmas, sine_t, tabs);
    igso3_gather<<<B, TPB, 0, stream>>>(sigmas, omegas, omega_grid, tabs, out);
  } else {
    igso3_main_nt<<<B, TPB, 0, stream>>>(sigmas, omegas, omega_grid,
                                         sine_terms, out);
  }
}